// Round 4
// baseline (240.291 us; speedup 1.0000x reference)
//
#include <hip/hip_runtime.h>

#define BATCH 8
#define SEQ   2048
#define EMB   1024
#define HD    64
#define HEADS 16
#define BS    (BATCH * SEQ)
#define LOG2E 1.4426950408889634f

typedef _Float16 half8 __attribute__((ext_vector_type(8)));
typedef _Float16 half4 __attribute__((ext_vector_type(4)));
typedef float    f32x4 __attribute__((ext_vector_type(4)));

__device__ __forceinline__ float fexp2(float x) {
#if __has_builtin(__builtin_amdgcn_exp2f)
    return __builtin_amdgcn_exp2f(x);
#else
    return exp2f(x);
#endif
}

__device__ __forceinline__ float frcp(float x) {
#if __has_builtin(__builtin_amdgcn_rcpf)
    return __builtin_amdgcn_rcpf(x);
#else
    return 1.0f / x;
#endif
}

// async global->LDS DMA: lane i deposits its element at lds_base + i*size.
__device__ __forceinline__ void dma16(void* lds_base, const void* gsrc) {
    __builtin_amdgcn_global_load_lds(
        (const __attribute__((address_space(1))) unsigned int*)gsrc,
        (__attribute__((address_space(3))) unsigned int*)lds_base, 16, 0, 0);
}

// ---------------- W -> fp16 (Wq pre-scaled by log2e: scores in log2 domain)
__global__ __launch_bounds__(256) void wcvt_kernel(
    const float* __restrict__ Wq, const float* __restrict__ Wk,
    const float* __restrict__ Wv, _Float16* __restrict__ Wh)
{
    const int m = blockIdx.y;
    const float* src = (m == 0) ? Wq : (m == 1) ? Wk : Wv;
    const float scale = (m == 0) ? LOG2E : 1.0f;
    const int idx = (blockIdx.x * 256 + threadIdx.x) * 8;
    float4 f0 = *(const float4*)(src + idx);
    float4 f1 = *(const float4*)(src + idx + 4);
    half8 h;
    h[0] = (_Float16)(f0.x * scale); h[1] = (_Float16)(f0.y * scale);
    h[2] = (_Float16)(f0.z * scale); h[3] = (_Float16)(f0.w * scale);
    h[4] = (_Float16)(f1.x * scale); h[5] = (_Float16)(f1.y * scale);
    h[6] = (_Float16)(f1.z * scale); h[7] = (_Float16)(f1.w * scale);
    *(half8*)(Wh + (size_t)m * 65536 + idx) = h;
}

// ---------------- QKV projection ----------------
// 1024 blocks x 256 thr (4 waves). Block = 16 rows x all 192 out-cols;
// wave=grp owns 3 ctiles. x (true 4-wave reuse) staged in LDS, 2x4KB
// double-buffer, 4 dma16 per chunk (1/wave). W loaded DIRECT global->VGPR,
// ping-pong prefetched one chunk ahead (statically indexed). Barrier only
// guards the tiny x stage -> far less drain per MFMA than before.
__global__ __launch_bounds__(256, 4) void qkv_kernel(
    const float* __restrict__ x, const _Float16* __restrict__ Wh,
    _Float16* __restrict__ qh, _Float16* __restrict__ kh, _Float16* __restrict__ vpt)
{
    __shared__ __align__(16) char arena[8192];   // x: 2 x 4KB
    const int t = threadIdx.x, lane = t & 63, wave = t >> 6;
    const int l15 = lane & 15, quad = lane >> 4;
    const int grp = wave;                         // [0,4): 3 ctiles each
    const int row0 = blockIdx.x * 16;

    auto issue = [&](int buf, int k0) {
        const int row = wave * 4 + (lane >> 4);
        const int logi = (lane & 15) ^ (row & 15);
        dma16((float*)(arena + buf * 4096) + wave * 256,
              x + (size_t)(row0 + row) * EMB + k0 + logi * 4);
    };
    auto loadW = [&](int k0, half8 (&w)[3][2]) {
        #pragma unroll
        for (int j = 0; j < 3; ++j) {
            const int g = (grp * 3 + j) * 16 + l15;            // W row [0,192)
            const _Float16* wp = Wh + (size_t)(g >> 6) * 65536
                               + (size_t)(g & 63) * EMB + k0 + quad * 8;
            w[j][0] = *(const half8*)(wp);
            w[j][1] = *(const half8*)(wp + 32);
        }
    };

    f32x4 acc[3] = {};
    auto step = [&](int buf, const half8 (&w)[3][2]) {
        const float* xb = (const float*)(arena + buf * 4096);
        half8 a[2];
        #pragma unroll
        for (int kc = 0; kc < 2; ++kc) {
            const int s0 = kc * 8 + quad * 2;
            f32x4 u0 = *(const f32x4*)(xb + l15 * 64 + ((s0    ) ^ l15) * 4);
            f32x4 u1 = *(const f32x4*)(xb + l15 * 64 + ((s0 + 1) ^ l15) * 4);
            a[kc][0] = (_Float16)u0[0]; a[kc][1] = (_Float16)u0[1];
            a[kc][2] = (_Float16)u0[2]; a[kc][3] = (_Float16)u0[3];
            a[kc][4] = (_Float16)u1[0]; a[kc][5] = (_Float16)u1[1];
            a[kc][6] = (_Float16)u1[2]; a[kc][7] = (_Float16)u1[3];
        }
        #pragma unroll
        for (int j = 0; j < 3; ++j) {
            acc[j] = __builtin_amdgcn_mfma_f32_16x16x32_f16(a[0], w[j][0], acc[j], 0, 0, 0);
            acc[j] = __builtin_amdgcn_mfma_f32_16x16x32_f16(a[1], w[j][1], acc[j], 0, 0, 0);
        }
    };

    half8 wA[3][2], wB[3][2];
    issue(0, 0);
    loadW(0, wA);
    __syncthreads();
    for (int it = 0; it < 16; it += 2) {
        // even chunk `it` in buf0 with wA; prefetch it+1
        issue(1, (it + 1) * 64);
        loadW((it + 1) * 64, wB);
        step(0, wA);
        __syncthreads();
        // odd chunk `it+1` in buf1 with wB; prefetch it+2
        if (it + 2 < 16) { issue(0, (it + 2) * 64); loadW((it + 2) * 64, wA); }
        step(1, wB);
        __syncthreads();
    }

    #pragma unroll
    for (int j = 0; j < 3; ++j) {
        const int c = grp * 3 + j, m = c >> 2, n = c & 3;
        if (m < 2) {
            _Float16* __restrict__ dst = (m == 0) ? qh : kh;
            #pragma unroll
            for (int r = 0; r < 4; ++r)
                dst[(size_t)(row0 + quad * 4 + r) * HD + n * 16 + l15] =
                    (_Float16)acc[j][r];
        } else {
            const int rg = row0 + quad * 4;
            const int b = rg >> 11, s = rg & 2047;
            half4 h;
            h[0] = (_Float16)acc[j][0]; h[1] = (_Float16)acc[j][1];
            h[2] = (_Float16)acc[j][2]; h[3] = (_Float16)acc[j][3];
            *(half4*)(vpt + ((size_t)b * HD + n * 16 + l15) * SEQ + s) = h;
        }
    }
}

// ---------------- Column-softmax partial denominators ----------------
// grid (64,8,2) x 256 thr (4 waves). Block = 32 keys (A-frags in regs);
// z = query-half. BARRIER-FREE stream loop: each wave loads its private
// 16-query B-frag DIRECT global->VGPR (no LDS), 4 MFMA + 16 exp per iter.
// Cross-wave sum via tiny LDS at the end only.
__global__ __launch_bounds__(256, 4) void stats_kernel(
    const _Float16* __restrict__ qh, const _Float16* __restrict__ kh,
    float* __restrict__ l_part)
{
    __shared__ float red[4][32];
    const int t = threadIdx.x, lane = t & 63, wave = t >> 6;
    const int l15 = lane & 15, quad = lane >> 4;
    const int b = blockIdx.y, c0 = blockIdx.x * 32, z = blockIdx.z;

    half8 ka[2][2];
    #pragma unroll
    for (int kt = 0; kt < 2; ++kt) {
        const _Float16* kp = kh + ((size_t)b * SEQ + c0 + kt * 16 + l15) * HD + quad * 8;
        ka[kt][0] = *(const half8*)(kp);
        ka[kt][1] = *(const half8*)(kp + 32);
    }

    const _Float16* qp0 = qh + ((size_t)b * SEQ + z * 1024 + wave * 16 + l15) * HD + quad * 8;
    float csum[2][4] = {};
    for (int it = 0; it < 16; ++it) {
        const _Float16* qp = qp0 + (size_t)it * 64 * HD;
        half8 bq0 = *(const half8*)(qp);
        half8 bq1 = *(const half8*)(qp + 32);
        f32x4 s0 = {}, s1 = {};
        s0 = __builtin_amdgcn_mfma_f32_16x16x32_f16(ka[0][0], bq0, s0, 0, 0, 0);
        s0 = __builtin_amdgcn_mfma_f32_16x16x32_f16(ka[0][1], bq1, s0, 0, 0, 0);
        s1 = __builtin_amdgcn_mfma_f32_16x16x32_f16(ka[1][0], bq0, s1, 0, 0, 0);
        s1 = __builtin_amdgcn_mfma_f32_16x16x32_f16(ka[1][1], bq1, s1, 0, 0, 0);
        #pragma unroll
        for (int r = 0; r < 4; ++r) {
            csum[0][r] += fexp2(s0[r]);
            csum[1][r] += fexp2(s1[r]);
        }
    }
    #pragma unroll
    for (int kt = 0; kt < 2; ++kt)
        #pragma unroll
        for (int r = 0; r < 4; ++r) {
            csum[kt][r] += __shfl_xor(csum[kt][r], 1);
            csum[kt][r] += __shfl_xor(csum[kt][r], 2);
            csum[kt][r] += __shfl_xor(csum[kt][r], 4);
            csum[kt][r] += __shfl_xor(csum[kt][r], 8);
        }
    if (l15 == 0) {
        #pragma unroll
        for (int kt = 0; kt < 2; ++kt)
            #pragma unroll
            for (int r = 0; r < 4; ++r)
                red[wave][kt * 16 + quad * 4 + r] = csum[kt][r];
    }
    __syncthreads();
    if (t < 32)
        l_part[(size_t)z * BS + (size_t)b * SEQ + c0 + t] =
            red[0][t] + red[1][t] + red[2][t] + red[3][t];
}

// ---------------- opart[z] = P~ @ v over key-half z ----------------
// grid (64,8,2) x 256 thr (4 waves): rw=(w&1) row-tile, kw=(w>>1) key-half
// of chunk. BARRIER-FREE stream loop over 16 chunks of 64 keys: K, V, l all
// loaded DIRECT global->VGPR. Only LDS use in loop: wave-private P transpose
// round-trip (compiler orders via lgkmcnt; no barrier). Cross-wave O
// reduction in disjoint LDS region at the end; compact f32 partial write.
__global__ __launch_bounds__(256, 4) void out_kernel(
    const _Float16* __restrict__ qh, const _Float16* __restrict__ kh,
    const _Float16* __restrict__ vpt, const float* __restrict__ l_part,
    float* __restrict__ opart)
{
    __shared__ __align__(16) char arena[22528];
    // [0,5120)       ps  [4][16][40] fp16 (wave-private quarters)
    // [5120,13824)   red [16? -> [2][16][68] f32]
    // [13824,22528)  fin [32][68] f32
    const int t = threadIdx.x, lane = t & 63, wave = t >> 6;
    const int l15 = lane & 15, quad = lane >> 4;
    const int rw = wave & 1, kw = wave >> 1;
    const int b = blockIdx.y, r0 = blockIdx.x * 32, z = blockIdx.z;
    const int kbase = z * 1024;

    half8 aq[2];
    {
        const _Float16* qp = qh + ((size_t)b * SEQ + r0 + rw * 16 + l15) * HD + quad * 8;
        aq[0] = *(const half8*)(qp);
        aq[1] = *(const half8*)(qp + 32);
    }

    const float* lp = l_part + (size_t)b * SEQ;   // partial z'=0; z'=1 at +BS
    _Float16* psb = (_Float16*)(arena) + wave * 640;
    f32x4 oacc[4] = {};
    for (int it = 0; it < 16; ++it) {
        const int c0 = kbase + it * 64;
        f32x4 s[2] = {};
        float li[2];
        #pragma unroll
        for (int ct = 0; ct < 2; ++ct) {
            const int key = c0 + kw * 32 + ct * 16 + l15;
            const _Float16* kp = kh + ((size_t)b * SEQ + key) * HD + quad * 8;
            half8 kf0 = *(const half8*)(kp);
            half8 kf1 = *(const half8*)(kp + 32);
            s[ct] = __builtin_amdgcn_mfma_f32_16x16x32_f16(aq[0], kf0, s[ct], 0, 0, 0);
            s[ct] = __builtin_amdgcn_mfma_f32_16x16x32_f16(aq[1], kf1, s[ct], 0, 0, 0);
            li[ct] = frcp(lp[key] + lp[BS + key]);
        }
        #pragma unroll
        for (int ct = 0; ct < 2; ++ct)
            #pragma unroll
            for (int r = 0; r < 4; ++r)
                psb[(quad * 4 + r) * 40 + ct * 16 + l15] =
                    (_Float16)(fexp2(s[ct][r]) * li[ct]);
        half8 pa = *(const half8*)(psb + l15 * 40 + quad * 8);
        #pragma unroll
        for (int n = 0; n < 4; ++n) {
            const int d = n * 16 + l15;
            half8 vf = *(const half8*)(vpt + ((size_t)b * HD + d) * SEQ
                                       + c0 + (kw * 4 + quad) * 8);
            oacc[n] = __builtin_amdgcn_mfma_f32_16x16x32_f16(pa, vf, oacc[n], 0, 0, 0);
        }
    }

    // cross-wave (key-half) reduction in disjoint LDS regions
    float* red = (float*)(arena + 5120);     // [2][16][68]
    float* fin = (float*)(arena + 13824);    // [32][68]
    if (kw == 1) {
        #pragma unroll
        for (int n = 0; n < 4; ++n)
            #pragma unroll
            for (int r = 0; r < 4; ++r)
                red[(rw * 16 + quad * 4 + r) * 68 + n * 16 + l15] = oacc[n][r];
    }
    __syncthreads();
    if (kw == 0) {
        #pragma unroll
        for (int n = 0; n < 4; ++n)
            #pragma unroll
            for (int r = 0; r < 4; ++r)
                fin[(rw * 16 + quad * 4 + r) * 68 + n * 16 + l15] =
                    oacc[n][r] + red[(rw * 16 + quad * 4 + r) * 68 + n * 16 + l15];
    }
    __syncthreads();

    // compact epilogue: 32x64 f32 tile -> opart[z], coalesced float4
    const int row = t >> 3, s8 = t & 7;
    float4 u0 = *(float4*)(fin + row * 68 + s8 * 8);
    float4 u1 = *(float4*)(fin + row * 68 + s8 * 8 + 4);
    float* dst = opart + (size_t)z * ((size_t)BS * HD)
               + ((size_t)b * SEQ + r0 + row) * HD + s8 * 8;
    *(float4*)(dst)     = u0;
    *(float4*)(dst + 4) = u1;
}

// ---------------- out[b,s,h*64+d] = opart[0][b,s,d] + opart[1][b,s,d] -----
__global__ __launch_bounds__(256) void bcast_kernel(
    const float* __restrict__ opart, float* __restrict__ out)
{
    const int row = blockIdx.x;          // [0, BS)
    const int t = threadIdx.x;
    const int d = (t * 4) & 63;
    const float* o0 = opart + (size_t)row * HD + d;
    const float* o1 = o0 + (size_t)BS * HD;
    float4 a = *(const float4*)o0;
    float4 c = *(const float4*)o1;
    float4 s;
    s.x = a.x + c.x; s.y = a.y + c.y; s.z = a.z + c.z; s.w = a.w + c.w;
    *(float4*)(out + (size_t)row * (HD * HEADS) + t * 4) = s;
}

extern "C" void kernel_launch(void* const* d_in, const int* in_sizes, int n_in,
                              void* d_out, int out_size, void* d_ws, size_t ws_size,
                              hipStream_t stream)
{
    const float* x  = (const float*)d_in[0];
    const float* Wq = (const float*)d_in[1];
    const float* Wk = (const float*)d_in[2];
    const float* Wv = (const float*)d_in[3];
    float* out = (float*)d_out;

    const size_t N = (size_t)BATCH * SEQ * HD;   // 1,048,576
    _Float16* qh  = (_Float16*)d_ws;
    _Float16* kh  = qh + N;
    _Float16* vpt = kh + N;
    _Float16* Wh  = vpt + N;                     // 3*64*1024 halves
    float* l_part = (float*)(Wh + 196608);       // [2][B][S] f32 (128 KB)
    float* opart  = l_part + 2 * BS;             // [2][B][S][64] f32 (8 MiB)

    wcvt_kernel <<<dim3(32, 3),    256, 0, stream>>>(Wq, Wk, Wv, Wh);
    qkv_kernel  <<<dim3(1024),     256, 0, stream>>>(x, Wh, qh, kh, vpt);
    stats_kernel<<<dim3(64, 8, 2), 256, 0, stream>>>(qh, kh, l_part);
    out_kernel  <<<dim3(64, 8, 2), 256, 0, stream>>>(qh, kh, vpt, l_part, opart);
    bcast_kernel<<<dim3(BS),       256, 0, stream>>>(opart, out);
}

// Round 5
// 193.688 us; speedup vs baseline: 1.2406x; 1.2406x over previous
//
#include <hip/hip_runtime.h>

#define BATCH 8
#define SEQ   2048
#define EMB   1024
#define HD    64
#define HEADS 16
#define BS    (BATCH * SEQ)
#define LOG2E 1.4426950408889634f

typedef _Float16 half8 __attribute__((ext_vector_type(8)));
typedef _Float16 half4 __attribute__((ext_vector_type(4)));
typedef float    f32x4 __attribute__((ext_vector_type(4)));

__device__ __forceinline__ float fexp2(float x) {
#if __has_builtin(__builtin_amdgcn_exp2f)
    return __builtin_amdgcn_exp2f(x);
#else
    return exp2f(x);
#endif
}

__device__ __forceinline__ float frcp(float x) {
#if __has_builtin(__builtin_amdgcn_rcpf)
    return __builtin_amdgcn_rcpf(x);
#else
    return 1.0f / x;
#endif
}

// async global->LDS DMA: lane i deposits its element at lds_base + i*size.
// lds_base must be wave-uniform; gsrc is per-lane.
__device__ __forceinline__ void dma16(void* lds_base, const void* gsrc) {
    __builtin_amdgcn_global_load_lds(
        (const __attribute__((address_space(1))) unsigned int*)gsrc,
        (__attribute__((address_space(3))) unsigned int*)lds_base, 16, 0, 0);
}

// ---------------- W -> fp16 (Wq pre-scaled by log2e: scores in log2 domain)
__global__ __launch_bounds__(256) void wcvt_kernel(
    const float* __restrict__ Wq, const float* __restrict__ Wk,
    const float* __restrict__ Wv, _Float16* __restrict__ Wh)
{
    const int m = blockIdx.y;
    const float* src = (m == 0) ? Wq : (m == 1) ? Wk : Wv;
    const float scale = (m == 0) ? LOG2E : 1.0f;
    const int idx = (blockIdx.x * 256 + threadIdx.x) * 8;
    float4 f0 = *(const float4*)(src + idx);
    float4 f1 = *(const float4*)(src + idx + 4);
    half8 h;
    h[0] = (_Float16)(f0.x * scale); h[1] = (_Float16)(f0.y * scale);
    h[2] = (_Float16)(f0.z * scale); h[3] = (_Float16)(f0.w * scale);
    h[4] = (_Float16)(f1.x * scale); h[5] = (_Float16)(f1.y * scale);
    h[6] = (_Float16)(f1.z * scale); h[7] = (_Float16)(f1.w * scale);
    *(half8*)(Wh + (size_t)m * 65536 + idx) = h;
}

// ---------------- QKV projection (round-1 structure, V in packed layout) ----
// 512 blocks x 512 thr (8 waves). Block = 32 rows, 12 ctiles; wave: strip=(w&1),
// grp=(w>>1) -> 3 ctiles. x (f32) + W (fp16) chunks staged by DMA, double-buffered,
// XOR-swizzled 16B granules; ONE vmcnt drain per chunk at the barrier.
// V written as vpk[b][s>>3][d][s&7] (8-key packed, d-minor) so that the PV
// B-fragment loads in out_kernel are fully coalesced.
__global__ __launch_bounds__(512) void qkv_kernel(
    const float* __restrict__ x, const _Float16* __restrict__ Wh,
    _Float16* __restrict__ qh, _Float16* __restrict__ kh, _Float16* __restrict__ vpk)
{
    __shared__ __align__(16) char arena[65536];  // x: 2x8KB, W: 2x24KB
    const int t = threadIdx.x, lane = t & 63, wave = t >> 6;
    const int l15 = lane & 15, quad = lane >> 4;
    const int strip = wave & 1, grp = wave >> 1;
    const int row0 = blockIdx.x * 32;

    auto issue = [&](int buf, int k0) {
        #pragma unroll
        for (int jj = 0; jj < 4; ++jj) {
            const int j = wave * 4 + jj;
            if (j < 8) {           // x: 8 instrs, 4 rows x 16 f32-segs each
                const int row = j * 4 + (lane >> 4);
                const int logi = (lane & 15) ^ (row & 15);
                dma16((float*)(arena + buf * 8192) + j * 256,
                      x + (size_t)(row0 + row) * EMB + k0 + logi * 4);
            } else {               // W: 24 instrs, 8 dd-rows x 8 half-segs each
                const int jw = j - 8;
                const int dd = jw * 8 + (lane >> 3);
                const int logi = (lane & 7) ^ (dd & 7);
                dma16((_Float16*)(arena + 16384 + buf * 24576) + jw * 512,
                      Wh + (size_t)(dd >> 6) * 65536 + (size_t)(dd & 63) * EMB
                         + k0 + logi * 8);
            }
        }
    };

    issue(0, 0);
    __syncthreads();

    f32x4 acc[3] = {};
    const int xrow = strip * 16 + l15;
    for (int it = 0; it < 16; ++it) {
        const int buf = it & 1;
        if (it + 1 < 16) issue(buf ^ 1, (it + 1) * 64);
        const float* xb = (const float*)(arena + buf * 8192);
        const _Float16* wb = (const _Float16*)(arena + 16384 + buf * 24576);
        half8 a[2];
        #pragma unroll
        for (int kc = 0; kc < 2; ++kc) {
            const int s0 = kc * 8 + quad * 2;
            f32x4 u0 = *(const f32x4*)(xb + xrow * 64 + ((s0    ) ^ (l15 & 15)) * 4);
            f32x4 u1 = *(const f32x4*)(xb + xrow * 64 + ((s0 + 1) ^ (l15 & 15)) * 4);
            a[kc][0] = (_Float16)u0[0]; a[kc][1] = (_Float16)u0[1];
            a[kc][2] = (_Float16)u0[2]; a[kc][3] = (_Float16)u0[3];
            a[kc][4] = (_Float16)u1[0]; a[kc][5] = (_Float16)u1[1];
            a[kc][6] = (_Float16)u1[2]; a[kc][7] = (_Float16)u1[3];
        }
        #pragma unroll
        for (int j = 0; j < 3; ++j) {
            const int dd = (grp * 3 + j) * 16 + l15;
            #pragma unroll
            for (int kc = 0; kc < 2; ++kc) {
                half8 bfr = *(const half8*)(wb + dd * 64
                              + (((kc * 4 + quad) ^ (l15 & 7)) * 8));
                acc[j] = __builtin_amdgcn_mfma_f32_16x16x32_f16(a[kc], bfr, acc[j], 0, 0, 0);
            }
        }
        __syncthreads();
    }

    #pragma unroll
    for (int j = 0; j < 3; ++j) {
        const int c = grp * 3 + j, m = c >> 2, n = c & 3;
        if (m < 2) {
            _Float16* __restrict__ dst = (m == 0) ? qh : kh;
            #pragma unroll
            for (int r = 0; r < 4; ++r)
                dst[(size_t)(row0 + strip * 16 + quad * 4 + r) * HD + n * 16 + l15] =
                    (_Float16)acc[j][r];
        } else {
            const int rg = row0 + strip * 16 + quad * 4;
            const int b = rg >> 11, s = rg & 2047;
            half4 h;
            h[0] = (_Float16)acc[j][0]; h[1] = (_Float16)acc[j][1];
            h[2] = (_Float16)acc[j][2]; h[3] = (_Float16)acc[j][3];
            // vpk[b][s>>3][d][s&7], d = n*16+l15; s % 4 == 0 -> 8B aligned
            *(half4*)(vpk + (((size_t)b * 256 + (s >> 3)) * 64 + n * 16 + l15) * 8
                          + (s & 7)) = h;
        }
    }
}

// ---------------- Column-softmax partial denominators ----------------
// grid (64,8,2) x 256 thr (4 waves). Block = 32 keys (A-frags in regs);
// z = query-half. BARRIER-FREE stream loop: each wave loads its private
// 16-query B-frag DIRECT global->VGPR (coalesced 16 rows x 64B), 4 MFMA +
// 16 exp per iter. Cross-wave sum via tiny LDS at the end only.
__global__ __launch_bounds__(256, 4) void stats_kernel(
    const _Float16* __restrict__ qh, const _Float16* __restrict__ kh,
    float* __restrict__ l_part)
{
    __shared__ float red[4][32];
    const int t = threadIdx.x, lane = t & 63, wave = t >> 6;
    const int l15 = lane & 15, quad = lane >> 4;
    const int b = blockIdx.y, c0 = blockIdx.x * 32, z = blockIdx.z;

    half8 ka[2][2];
    #pragma unroll
    for (int kt = 0; kt < 2; ++kt) {
        const _Float16* kp = kh + ((size_t)b * SEQ + c0 + kt * 16 + l15) * HD + quad * 8;
        ka[kt][0] = *(const half8*)(kp);
        ka[kt][1] = *(const half8*)(kp + 32);
    }

    const _Float16* qp0 = qh + ((size_t)b * SEQ + z * 1024 + wave * 16 + l15) * HD + quad * 8;
    float csum[2][4] = {};
    for (int it = 0; it < 16; ++it) {
        const _Float16* qp = qp0 + (size_t)it * 64 * HD;
        half8 bq0 = *(const half8*)(qp);
        half8 bq1 = *(const half8*)(qp + 32);
        f32x4 s0 = {}, s1 = {};
        s0 = __builtin_amdgcn_mfma_f32_16x16x32_f16(ka[0][0], bq0, s0, 0, 0, 0);
        s0 = __builtin_amdgcn_mfma_f32_16x16x32_f16(ka[0][1], bq1, s0, 0, 0, 0);
        s1 = __builtin_amdgcn_mfma_f32_16x16x32_f16(ka[1][0], bq0, s1, 0, 0, 0);
        s1 = __builtin_amdgcn_mfma_f32_16x16x32_f16(ka[1][1], bq1, s1, 0, 0, 0);
        #pragma unroll
        for (int r = 0; r < 4; ++r) {
            csum[0][r] += fexp2(s0[r]);
            csum[1][r] += fexp2(s1[r]);
        }
    }
    #pragma unroll
    for (int kt = 0; kt < 2; ++kt)
        #pragma unroll
        for (int r = 0; r < 4; ++r) {
            csum[kt][r] += __shfl_xor(csum[kt][r], 1);
            csum[kt][r] += __shfl_xor(csum[kt][r], 2);
            csum[kt][r] += __shfl_xor(csum[kt][r], 4);
            csum[kt][r] += __shfl_xor(csum[kt][r], 8);
        }
    if (l15 == 0) {
        #pragma unroll
        for (int kt = 0; kt < 2; ++kt)
            #pragma unroll
            for (int r = 0; r < 4; ++r)
                red[wave][kt * 16 + quad * 4 + r] = csum[kt][r];
    }
    __syncthreads();
    if (t < 32)
        l_part[(size_t)z * BS + (size_t)b * SEQ + c0 + t] =
            red[0][t] + red[1][t] + red[2][t] + red[3][t];
}

// ---------------- opart[z] = P~ @ v over key-half z ----------------
// grid (64,8,2) x 256 thr (4 waves): rw=(w&1) row-tile, kw=(w>>1) key-half
// of chunk. BARRIER-FREE stream loop over 16 chunks of 64 keys: K, V, l all
// DIRECT global->VGPR. V now comes from the PACKED vpk[b][kb][d][kk] layout,
// so lanes (l15 = consecutive d) are contiguous -> 4x256B per load instr
// instead of 64 scattered lines (the round-4 regression). Only in-loop LDS:
// wave-private P transpose round trip (lgkmcnt-ordered, no barrier).
__global__ __launch_bounds__(256, 4) void out_kernel(
    const _Float16* __restrict__ qh, const _Float16* __restrict__ kh,
    const _Float16* __restrict__ vpk, const float* __restrict__ l_part,
    float* __restrict__ opart)
{
    __shared__ __align__(16) char arena[22528];
    // [0,5120)       ps  [4][16][40] fp16 (wave-private quarters)
    // [5120,13824)   red [2][16][68] f32
    // [13824,22528)  fin [32][68] f32
    const int t = threadIdx.x, lane = t & 63, wave = t >> 6;
    const int l15 = lane & 15, quad = lane >> 4;
    const int rw = wave & 1, kw = wave >> 1;
    const int b = blockIdx.y, r0 = blockIdx.x * 32, z = blockIdx.z;
    const int kbase = z * 1024;

    half8 aq[2];
    {
        const _Float16* qp = qh + ((size_t)b * SEQ + r0 + rw * 16 + l15) * HD + quad * 8;
        aq[0] = *(const half8*)(qp);
        aq[1] = *(const half8*)(qp + 32);
    }

    const float* lp = l_part + (size_t)b * SEQ;   // partial z'=0; z'=1 at +BS
    _Float16* psb = (_Float16*)(arena) + wave * 640;
    f32x4 oacc[4] = {};
    for (int it = 0; it < 16; ++it) {
        const int c0 = kbase + it * 64;
        f32x4 s[2] = {};
        float li[2];
        #pragma unroll
        for (int ct = 0; ct < 2; ++ct) {
            const int key = c0 + kw * 32 + ct * 16 + l15;
            const _Float16* kp = kh + ((size_t)b * SEQ + key) * HD + quad * 8;
            half8 kf0 = *(const half8*)(kp);
            half8 kf1 = *(const half8*)(kp + 32);
            s[ct] = __builtin_amdgcn_mfma_f32_16x16x32_f16(aq[0], kf0, s[ct], 0, 0, 0);
            s[ct] = __builtin_amdgcn_mfma_f32_16x16x32_f16(aq[1], kf1, s[ct], 0, 0, 0);
            li[ct] = frcp(lp[key] + lp[BS + key]);
        }
        #pragma unroll
        for (int ct = 0; ct < 2; ++ct)
            #pragma unroll
            for (int r = 0; r < 4; ++r)
                psb[(quad * 4 + r) * 40 + ct * 16 + l15] =
                    (_Float16)(fexp2(s[ct][r]) * li[ct]);
        half8 pa = *(const half8*)(psb + l15 * 40 + quad * 8);
        // packed V: kb = c0/8 + (kw*4+quad); lane reads d = n*16+l15 (contiguous)
        const _Float16* vbase = vpk
            + ((size_t)b * 256 + (c0 >> 3) + kw * 4 + quad) * 512;
        #pragma unroll
        for (int n = 0; n < 4; ++n) {
            half8 vf = *(const half8*)(vbase + (n * 16 + l15) * 8);
            oacc[n] = __builtin_amdgcn_mfma_f32_16x16x32_f16(pa, vf, oacc[n], 0, 0, 0);
        }
    }

    // cross-wave (key-half) reduction in disjoint LDS regions
    float* red = (float*)(arena + 5120);     // [2][16][68]
    float* fin = (float*)(arena + 13824);    // [32][68]
    if (kw == 1) {
        #pragma unroll
        for (int n = 0; n < 4; ++n)
            #pragma unroll
            for (int r = 0; r < 4; ++r)
                red[(rw * 16 + quad * 4 + r) * 68 + n * 16 + l15] = oacc[n][r];
    }
    __syncthreads();
    if (kw == 0) {
        #pragma unroll
        for (int n = 0; n < 4; ++n)
            #pragma unroll
            for (int r = 0; r < 4; ++r)
                fin[(rw * 16 + quad * 4 + r) * 68 + n * 16 + l15] =
                    oacc[n][r] + red[(rw * 16 + quad * 4 + r) * 68 + n * 16 + l15];
    }
    __syncthreads();

    // compact epilogue: 32x64 f32 tile -> opart[z], coalesced float4
    const int row = t >> 3, s8 = t & 7;
    float4 u0 = *(float4*)(fin + row * 68 + s8 * 8);
    float4 u1 = *(float4*)(fin + row * 68 + s8 * 8 + 4);
    float* dst = opart + (size_t)z * ((size_t)BS * HD)
               + ((size_t)b * SEQ + r0 + row) * HD + s8 * 8;
    *(float4*)(dst)     = u0;
    *(float4*)(dst + 4) = u1;
}

// ---------------- out[b,s,h*64+d] = opart[0][b,s,d] + opart[1][b,s,d] -----
__global__ __launch_bounds__(256) void bcast_kernel(
    const float* __restrict__ opart, float* __restrict__ out)
{
    const int row = blockIdx.x;          // [0, BS)
    const int t = threadIdx.x;
    const int d = (t * 4) & 63;
    const float* o0 = opart + (size_t)row * HD + d;
    const float* o1 = o0 + (size_t)BS * HD;
    float4 a = *(const float4*)o0;
    float4 c = *(const float4*)o1;
    float4 s;
    s.x = a.x + c.x; s.y = a.y + c.y; s.z = a.z + c.z; s.w = a.w + c.w;
    *(float4*)(out + (size_t)row * (HD * HEADS) + t * 4) = s;
}

extern "C" void kernel_launch(void* const* d_in, const int* in_sizes, int n_in,
                              void* d_out, int out_size, void* d_ws, size_t ws_size,
                              hipStream_t stream)
{
    const float* x  = (const float*)d_in[0];
    const float* Wq = (const float*)d_in[1];
    const float* Wk = (const float*)d_in[2];
    const float* Wv = (const float*)d_in[3];
    float* out = (float*)d_out;

    const size_t N = (size_t)BATCH * SEQ * HD;   // 1,048,576
    _Float16* qh  = (_Float16*)d_ws;
    _Float16* kh  = qh + N;
    _Float16* vpk = kh + N;
    _Float16* Wh  = vpk + N;                     // 3*64*1024 halves
    float* l_part = (float*)(Wh + 196608);       // [2][B][S] f32 (128 KB)
    float* opart  = l_part + 2 * BS;             // [2][B][S][64] f32 (8 MiB)

    wcvt_kernel <<<dim3(32, 3),    256, 0, stream>>>(Wq, Wk, Wv, Wh);
    qkv_kernel  <<<dim3(512),      512, 0, stream>>>(x, Wh, qh, kh, vpk);
    stats_kernel<<<dim3(64, 8, 2), 256, 0, stream>>>(qh, kh, l_part);
    out_kernel  <<<dim3(64, 8, 2), 256, 0, stream>>>(qh, kh, vpk, l_part, opart);
    bcast_kernel<<<dim3(BS),       256, 0, stream>>>(opart, out);
}

// Round 6
// 193.299 us; speedup vs baseline: 1.2431x; 1.0020x over previous
//
#include <hip/hip_runtime.h>

#define BATCH 8
#define SEQ   2048
#define EMB   1024
#define HD    64
#define HEADS 16
#define BS    (BATCH * SEQ)
#define LOG2E 1.4426950408889634f

typedef _Float16 half8 __attribute__((ext_vector_type(8)));
typedef _Float16 half4 __attribute__((ext_vector_type(4)));
typedef float    f32x4 __attribute__((ext_vector_type(4)));

__device__ __forceinline__ float fexp2(float x) {
#if __has_builtin(__builtin_amdgcn_exp2f)
    return __builtin_amdgcn_exp2f(x);
#else
    return exp2f(x);
#endif
}

__device__ __forceinline__ float frcp(float x) {
#if __has_builtin(__builtin_amdgcn_rcpf)
    return __builtin_amdgcn_rcpf(x);
#else
    return 1.0f / x;
#endif
}

// async global->LDS DMA: lane i deposits its element at lds_base + i*size.
// lds_base must be wave-uniform; gsrc is per-lane.
__device__ __forceinline__ void dma16(void* lds_base, const void* gsrc) {
    __builtin_amdgcn_global_load_lds(
        (const __attribute__((address_space(1))) unsigned int*)gsrc,
        (__attribute__((address_space(3))) unsigned int*)lds_base, 16, 0, 0);
}

// ---------------- W -> fp16 (Wq pre-scaled by log2e: scores in log2 domain)
__global__ __launch_bounds__(256) void wcvt_kernel(
    const float* __restrict__ Wq, const float* __restrict__ Wk,
    const float* __restrict__ Wv, _Float16* __restrict__ Wh)
{
    const int m = blockIdx.y;
    const float* src = (m == 0) ? Wq : (m == 1) ? Wk : Wv;
    const float scale = (m == 0) ? LOG2E : 1.0f;
    const int idx = (blockIdx.x * 256 + threadIdx.x) * 8;
    float4 f0 = *(const float4*)(src + idx);
    float4 f1 = *(const float4*)(src + idx + 4);
    half8 h;
    h[0] = (_Float16)(f0.x * scale); h[1] = (_Float16)(f0.y * scale);
    h[2] = (_Float16)(f0.z * scale); h[3] = (_Float16)(f0.w * scale);
    h[4] = (_Float16)(f1.x * scale); h[5] = (_Float16)(f1.y * scale);
    h[6] = (_Float16)(f1.z * scale); h[7] = (_Float16)(f1.w * scale);
    *(half8*)(Wh + (size_t)m * 65536 + idx) = h;
}

// ---------------- QKV projection (proven r0/r1 structure, packed-V epilogue)
// 512 blocks x 512 thr (8 waves). Block = 32 rows, 12 ctiles; wave: strip=(w&1),
// grp=(w>>1) -> 3 ctiles. x (f32) + W (fp16) chunks staged by DMA, double-buffered,
// XOR-swizzled 16B granules; ONE vmcnt drain per chunk at the barrier.
// V written as vpk[b][s>>3][d][s&7] (8-key packed, d-minor) so PV B-fragment
// loads in out_kernel are fully coalesced.
__global__ __launch_bounds__(512) void qkv_kernel(
    const float* __restrict__ x, const _Float16* __restrict__ Wh,
    _Float16* __restrict__ qh, _Float16* __restrict__ kh, _Float16* __restrict__ vpk)
{
    __shared__ __align__(16) char arena[65536];  // x: 2x8KB, W: 2x24KB
    const int t = threadIdx.x, lane = t & 63, wave = t >> 6;
    const int l15 = lane & 15, quad = lane >> 4;
    const int strip = wave & 1, grp = wave >> 1;
    const int row0 = blockIdx.x * 32;

    auto issue = [&](int buf, int k0) {
        #pragma unroll
        for (int jj = 0; jj < 4; ++jj) {
            const int j = wave * 4 + jj;
            if (j < 8) {           // x: 8 instrs, 4 rows x 16 f32-segs each
                const int row = j * 4 + (lane >> 4);
                const int logi = (lane & 15) ^ (row & 15);
                dma16((float*)(arena + buf * 8192) + j * 256,
                      x + (size_t)(row0 + row) * EMB + k0 + logi * 4);
            } else {               // W: 24 instrs, 8 dd-rows x 8 half-segs each
                const int jw = j - 8;
                const int dd = jw * 8 + (lane >> 3);
                const int logi = (lane & 7) ^ (dd & 7);
                dma16((_Float16*)(arena + 16384 + buf * 24576) + jw * 512,
                      Wh + (size_t)(dd >> 6) * 65536 + (size_t)(dd & 63) * EMB
                         + k0 + logi * 8);
            }
        }
    };

    issue(0, 0);
    __syncthreads();

    f32x4 acc[3] = {};
    const int xrow = strip * 16 + l15;
    for (int it = 0; it < 16; ++it) {
        const int buf = it & 1;
        if (it + 1 < 16) issue(buf ^ 1, (it + 1) * 64);
        const float* xb = (const float*)(arena + buf * 8192);
        const _Float16* wb = (const _Float16*)(arena + 16384 + buf * 24576);
        half8 a[2];
        #pragma unroll
        for (int kc = 0; kc < 2; ++kc) {
            const int s0 = kc * 8 + quad * 2;
            f32x4 u0 = *(const f32x4*)(xb + xrow * 64 + ((s0    ) ^ (l15 & 15)) * 4);
            f32x4 u1 = *(const f32x4*)(xb + xrow * 64 + ((s0 + 1) ^ (l15 & 15)) * 4);
            a[kc][0] = (_Float16)u0[0]; a[kc][1] = (_Float16)u0[1];
            a[kc][2] = (_Float16)u0[2]; a[kc][3] = (_Float16)u0[3];
            a[kc][4] = (_Float16)u1[0]; a[kc][5] = (_Float16)u1[1];
            a[kc][6] = (_Float16)u1[2]; a[kc][7] = (_Float16)u1[3];
        }
        #pragma unroll
        for (int j = 0; j < 3; ++j) {
            const int dd = (grp * 3 + j) * 16 + l15;
            #pragma unroll
            for (int kc = 0; kc < 2; ++kc) {
                half8 bfr = *(const half8*)(wb + dd * 64
                              + (((kc * 4 + quad) ^ (l15 & 7)) * 8));
                acc[j] = __builtin_amdgcn_mfma_f32_16x16x32_f16(a[kc], bfr, acc[j], 0, 0, 0);
            }
        }
        __syncthreads();
    }

    #pragma unroll
    for (int j = 0; j < 3; ++j) {
        const int c = grp * 3 + j, m = c >> 2, n = c & 3;
        if (m < 2) {
            _Float16* __restrict__ dst = (m == 0) ? qh : kh;
            #pragma unroll
            for (int r = 0; r < 4; ++r)
                dst[(size_t)(row0 + strip * 16 + quad * 4 + r) * HD + n * 16 + l15] =
                    (_Float16)acc[j][r];
        } else {
            const int rg = row0 + strip * 16 + quad * 4;
            const int b = rg >> 11, s = rg & 2047;
            half4 h;
            h[0] = (_Float16)acc[j][0]; h[1] = (_Float16)acc[j][1];
            h[2] = (_Float16)acc[j][2]; h[3] = (_Float16)acc[j][3];
            // vpk[b][s>>3][d][s&7], d = n*16+l15; s % 4 == 0 -> 8B aligned
            *(half4*)(vpk + (((size_t)b * 256 + (s >> 3)) * 64 + n * 16 + l15) * 8
                          + (s & 7)) = h;
        }
    }
}

// ---------------- Column-softmax partial denominators ----------------
// grid (64,8,2) x 256 thr (4 waves). Block = 32 keys (A-frags in regs);
// z = query-half. BARRIER-FREE stream loop, 2-deep explicit register
// prefetch (named A/B sets; B-frag for chunk i+1 in flight during chunk i's
// MFMA+exp). Cross-wave sum via tiny LDS at the end only.
__global__ __launch_bounds__(256, 4) void stats_kernel(
    const _Float16* __restrict__ qh, const _Float16* __restrict__ kh,
    float* __restrict__ l_part)
{
    __shared__ float red[4][32];
    const int t = threadIdx.x, lane = t & 63, wave = t >> 6;
    const int l15 = lane & 15, quad = lane >> 4;
    const int b = blockIdx.y, c0 = blockIdx.x * 32, z = blockIdx.z;

    half8 ka[2][2];
    #pragma unroll
    for (int kt = 0; kt < 2; ++kt) {
        const _Float16* kp = kh + ((size_t)b * SEQ + c0 + kt * 16 + l15) * HD + quad * 8;
        ka[kt][0] = *(const half8*)(kp);
        ka[kt][1] = *(const half8*)(kp + 32);
    }

    const _Float16* qp0 = qh + ((size_t)b * SEQ + z * 1024 + wave * 16 + l15) * HD + quad * 8;
    float csum[2][4] = {};

    auto accum = [&](half8 bq0, half8 bq1) {
        f32x4 s0 = {}, s1 = {};
        s0 = __builtin_amdgcn_mfma_f32_16x16x32_f16(ka[0][0], bq0, s0, 0, 0, 0);
        s0 = __builtin_amdgcn_mfma_f32_16x16x32_f16(ka[0][1], bq1, s0, 0, 0, 0);
        s1 = __builtin_amdgcn_mfma_f32_16x16x32_f16(ka[1][0], bq0, s1, 0, 0, 0);
        s1 = __builtin_amdgcn_mfma_f32_16x16x32_f16(ka[1][1], bq1, s1, 0, 0, 0);
        #pragma unroll
        for (int r = 0; r < 4; ++r) {
            csum[0][r] += fexp2(s0[r]);
            csum[1][r] += fexp2(s1[r]);
        }
    };

    half8 bqA0 = *(const half8*)(qp0);
    half8 bqA1 = *(const half8*)(qp0 + 32);
    for (int it = 0; it < 16; it += 2) {
        const _Float16* qpB = qp0 + (size_t)(it + 1) * 64 * HD;
        half8 bqB0 = *(const half8*)(qpB);
        half8 bqB1 = *(const half8*)(qpB + 32);
        accum(bqA0, bqA1);
        if (it + 2 < 16) {
            const _Float16* qpA = qp0 + (size_t)(it + 2) * 64 * HD;
            bqA0 = *(const half8*)(qpA);
            bqA1 = *(const half8*)(qpA + 32);
        }
        accum(bqB0, bqB1);
    }

    #pragma unroll
    for (int kt = 0; kt < 2; ++kt)
        #pragma unroll
        for (int r = 0; r < 4; ++r) {
            csum[kt][r] += __shfl_xor(csum[kt][r], 1);
            csum[kt][r] += __shfl_xor(csum[kt][r], 2);
            csum[kt][r] += __shfl_xor(csum[kt][r], 4);
            csum[kt][r] += __shfl_xor(csum[kt][r], 8);
        }
    if (l15 == 0) {
        #pragma unroll
        for (int kt = 0; kt < 2; ++kt)
            #pragma unroll
            for (int r = 0; r < 4; ++r)
                red[wave][kt * 16 + quad * 4 + r] = csum[kt][r];
    }
    __syncthreads();
    if (t < 32)
        l_part[(size_t)z * BS + (size_t)b * SEQ + c0 + t] =
            red[0][t] + red[1][t] + red[2][t] + red[3][t];
}

// ---------------- out = P~ @ v, fused x16-head broadcast epilogue ----------
// grid (64,8) x 256 thr (4 waves): rw=(w&1) row-tile, kw=(w>>1) key-half of
// each 64-key chunk. 32 chunks cover all keys. BARRIER-FREE stream loop:
// K (row-major) and V (packed vpk[b][kb][d][kk]) DIRECT global->VGPR with
// 2-deep named-A/B register prefetch; l = 1/(l0+l1) in-register. DUAL psb
// buffers (iter parity) remove the WAR that serialized the LDS transpose
// round-trip across iterations. Cross-wave O reduction + x16-head coalesced
// broadcast write (no separate bcast kernel).
__global__ __launch_bounds__(256, 4) void out_kernel(
    const _Float16* __restrict__ qh, const _Float16* __restrict__ kh,
    const _Float16* __restrict__ vpk, const float* __restrict__ l_part,
    float* __restrict__ out)
{
    __shared__ __align__(16) char arena[27648];
    // [0,10240)      ps  [4 waves][2 bufs][16][40] fp16
    // [10240,18944)  red [2][16][68] f32
    // [18944,27648)  fin [32][68] f32
    const int t = threadIdx.x, lane = t & 63, wave = t >> 6;
    const int l15 = lane & 15, quad = lane >> 4;
    const int rw = wave & 1, kw = wave >> 1;
    const int b = blockIdx.y, r0 = blockIdx.x * 32;

    half8 aq[2];
    {
        const _Float16* qp = qh + ((size_t)b * SEQ + r0 + rw * 16 + l15) * HD + quad * 8;
        aq[0] = *(const half8*)(qp);
        aq[1] = *(const half8*)(qp + 32);
    }

    const float* lp = l_part + (size_t)b * SEQ;   // z'=0; z'=1 at +BS
    _Float16* psA = (_Float16*)(arena) + wave * 1280;
    _Float16* psB = psA + 640;

    auto loadRegs = [&](int it, half8 (&kf)[2][2], half8 (&vf)[4],
                        float (&l0)[2], float (&l1)[2]) {
        const int c0 = it * 64;
        #pragma unroll
        for (int ct = 0; ct < 2; ++ct) {
            const int key = c0 + kw * 32 + ct * 16 + l15;
            const _Float16* kp = kh + ((size_t)b * SEQ + key) * HD + quad * 8;
            kf[ct][0] = *(const half8*)(kp);
            kf[ct][1] = *(const half8*)(kp + 32);
            l0[ct] = lp[key];
            l1[ct] = lp[BS + key];
        }
        const _Float16* vbase = vpk
            + ((size_t)b * 256 + (c0 >> 3) + kw * 4 + quad) * 512;
        #pragma unroll
        for (int n = 0; n < 4; ++n)
            vf[n] = *(const half8*)(vbase + (n * 16 + l15) * 8);
    };

    f32x4 oacc[4] = {};
    auto compute = [&](const half8 (&kf)[2][2], const half8 (&vf)[4],
                       const float (&l0)[2], const float (&l1)[2],
                       _Float16* psb) {
        f32x4 s[2] = {};
        #pragma unroll
        for (int ct = 0; ct < 2; ++ct) {
            s[ct] = __builtin_amdgcn_mfma_f32_16x16x32_f16(aq[0], kf[ct][0], s[ct], 0, 0, 0);
            s[ct] = __builtin_amdgcn_mfma_f32_16x16x32_f16(aq[1], kf[ct][1], s[ct], 0, 0, 0);
        }
        #pragma unroll
        for (int ct = 0; ct < 2; ++ct) {
            const float li = frcp(l0[ct] + l1[ct]);
            #pragma unroll
            for (int r = 0; r < 4; ++r)
                psb[(quad * 4 + r) * 40 + ct * 16 + l15] =
                    (_Float16)(fexp2(s[ct][r]) * li);
        }
        half8 pa = *(const half8*)(psb + l15 * 40 + quad * 8);
        #pragma unroll
        for (int n = 0; n < 4; ++n)
            oacc[n] = __builtin_amdgcn_mfma_f32_16x16x32_f16(pa, vf[n], oacc[n], 0, 0, 0);
    };

    half8 kfA[2][2], vfA[4], kfB[2][2], vfB[4];
    float l0A[2], l1A[2], l0B[2], l1B[2];
    loadRegs(0, kfA, vfA, l0A, l1A);
    for (int it = 0; it < 32; it += 2) {
        loadRegs(it + 1, kfB, vfB, l0B, l1B);   // in flight during compute-A
        compute(kfA, vfA, l0A, l1A, psA);
        if (it + 2 < 32)
            loadRegs(it + 2, kfA, vfA, l0A, l1A);  // in flight during compute-B
        compute(kfB, vfB, l0B, l1B, psB);
    }

    // cross-wave (key-half) reduction in disjoint LDS regions
    float* red = (float*)(arena + 10240);    // [2][16][68]
    float* fin = (float*)(arena + 18944);    // [32][68]
    if (kw == 1) {
        #pragma unroll
        for (int n = 0; n < 4; ++n)
            #pragma unroll
            for (int r = 0; r < 4; ++r)
                red[(rw * 16 + quad * 4 + r) * 68 + n * 16 + l15] = oacc[n][r];
    }
    __syncthreads();
    if (kw == 0) {
        #pragma unroll
        for (int n = 0; n < 4; ++n)
            #pragma unroll
            for (int r = 0; r < 4; ++r)
                fin[(rw * 16 + quad * 4 + r) * 68 + n * 16 + l15] =
                    oacc[n][r] + red[(rw * 16 + quad * 4 + r) * 68 + n * 16 + l15];
    }
    __syncthreads();

    // epilogue: 32x64 f32 tile -> 16 head slots, coalesced float4
    const int row = t >> 3, s8 = t & 7;
    float4 u0 = *(float4*)(fin + row * 68 + s8 * 8);
    float4 u1 = *(float4*)(fin + row * 68 + s8 * 8 + 4);
    size_t base = ((size_t)b * SEQ + r0 + row) * (HD * HEADS);
    #pragma unroll
    for (int h = 0; h < HEADS; ++h) {
        *(float4*)&out[base + h * HD + s8 * 8]     = u0;
        *(float4*)&out[base + h * HD + s8 * 8 + 4] = u1;
    }
}

extern "C" void kernel_launch(void* const* d_in, const int* in_sizes, int n_in,
                              void* d_out, int out_size, void* d_ws, size_t ws_size,
                              hipStream_t stream)
{
    const float* x  = (const float*)d_in[0];
    const float* Wq = (const float*)d_in[1];
    const float* Wk = (const float*)d_in[2];
    const float* Wv = (const float*)d_in[3];
    float* out = (float*)d_out;

    const size_t N = (size_t)BATCH * SEQ * HD;   // 1,048,576
    _Float16* qh  = (_Float16*)d_ws;
    _Float16* kh  = qh + N;
    _Float16* vpk = kh + N;
    _Float16* Wh  = vpk + N;                     // 3*64*1024 halves
    float* l_part = (float*)(Wh + 196608);       // [2][B][S] f32 (128 KB)

    wcvt_kernel <<<dim3(32, 3),    256, 0, stream>>>(Wq, Wk, Wv, Wh);
    qkv_kernel  <<<dim3(512),      512, 0, stream>>>(x, Wh, qh, kh, vpk);
    stats_kernel<<<dim3(64, 8, 2), 256, 0, stream>>>(qh, kh, l_part);
    out_kernel  <<<dim3(64, 8),    256, 0, stream>>>(qh, kh, vpk, l_part, out);
}

// Round 7
// 174.794 us; speedup vs baseline: 1.3747x; 1.1059x over previous
//
#include <hip/hip_runtime.h>

#define BATCH 8
#define SEQ   2048
#define EMB   1024
#define HD    64
#define HEADS 16
#define BS    (BATCH * SEQ)
#define LOG2E 1.4426950408889634f

typedef _Float16 half8 __attribute__((ext_vector_type(8)));
typedef _Float16 half4 __attribute__((ext_vector_type(4)));
typedef float    f32x4 __attribute__((ext_vector_type(4)));

__device__ __forceinline__ float fexp2(float x) {
#if __has_builtin(__builtin_amdgcn_exp2f)
    return __builtin_amdgcn_exp2f(x);
#else
    return exp2f(x);
#endif
}

__device__ __forceinline__ float frcp(float x) {
#if __has_builtin(__builtin_amdgcn_rcpf)
    return __builtin_amdgcn_rcpf(x);
#else
    return 1.0f / x;
#endif
}

// async global->LDS DMA: lane i deposits its element at lds_base + i*size.
// lds_base must be wave-uniform; gsrc is per-lane.
__device__ __forceinline__ void dma16(void* lds_base, const void* gsrc) {
    __builtin_amdgcn_global_load_lds(
        (const __attribute__((address_space(1))) unsigned int*)gsrc,
        (__attribute__((address_space(3))) unsigned int*)lds_base, 16, 0, 0);
}

// ---------------- W -> fp16 (Wq pre-scaled by log2e: scores in log2 domain)
__global__ __launch_bounds__(256) void wcvt_kernel(
    const float* __restrict__ Wq, const float* __restrict__ Wk,
    const float* __restrict__ Wv, _Float16* __restrict__ Wh)
{
    const int m = blockIdx.y;
    const float* src = (m == 0) ? Wq : (m == 1) ? Wk : Wv;
    const float scale = (m == 0) ? LOG2E : 1.0f;
    const int idx = (blockIdx.x * 256 + threadIdx.x) * 8;
    float4 f0 = *(const float4*)(src + idx);
    float4 f1 = *(const float4*)(src + idx + 4);
    half8 h;
    h[0] = (_Float16)(f0.x * scale); h[1] = (_Float16)(f0.y * scale);
    h[2] = (_Float16)(f0.z * scale); h[3] = (_Float16)(f0.w * scale);
    h[4] = (_Float16)(f1.x * scale); h[5] = (_Float16)(f1.y * scale);
    h[6] = (_Float16)(f1.z * scale); h[7] = (_Float16)(f1.w * scale);
    *(half8*)(Wh + (size_t)m * 65536 + idx) = h;
}

// ---------------- QKV projection (r1-exact, proven) ----------------
// 512 blocks x 512 thr (8 waves). Block = 32 rows, 12 ctiles; wave: strip=(w&1),
// grp=(w>>1) -> 3 ctiles. x (f32) + W (fp16) chunks staged by DMA, double-buffered,
// XOR-swizzled 16B granules; ONE vmcnt drain per chunk at the barrier.
__global__ __launch_bounds__(512) void qkv_kernel(
    const float* __restrict__ x, const _Float16* __restrict__ Wh,
    _Float16* __restrict__ qh, _Float16* __restrict__ kh, _Float16* __restrict__ vpt)
{
    __shared__ __align__(16) char arena[65536];  // x: 2x8KB, W: 2x24KB
    const int t = threadIdx.x, lane = t & 63, wave = t >> 6;
    const int l15 = lane & 15, quad = lane >> 4;
    const int strip = wave & 1, grp = wave >> 1;
    const int row0 = blockIdx.x * 32;

    auto issue = [&](int buf, int k0) {
        #pragma unroll
        for (int jj = 0; jj < 4; ++jj) {
            const int j = wave * 4 + jj;
            if (j < 8) {           // x: 8 instrs, 4 rows x 16 f32-segs each
                const int row = j * 4 + (lane >> 4);
                const int logi = (lane & 15) ^ (row & 15);
                dma16((float*)(arena + buf * 8192) + j * 256,
                      x + (size_t)(row0 + row) * EMB + k0 + logi * 4);
            } else {               // W: 24 instrs, 8 dd-rows x 8 half-segs each
                const int jw = j - 8;
                const int dd = jw * 8 + (lane >> 3);
                const int logi = (lane & 7) ^ (dd & 7);
                dma16((_Float16*)(arena + 16384 + buf * 24576) + jw * 512,
                      Wh + (size_t)(dd >> 6) * 65536 + (size_t)(dd & 63) * EMB
                         + k0 + logi * 8);
            }
        }
    };

    issue(0, 0);
    __syncthreads();

    f32x4 acc[3] = {};
    const int xrow = strip * 16 + l15;
    for (int it = 0; it < 16; ++it) {
        const int buf = it & 1;
        if (it + 1 < 16) issue(buf ^ 1, (it + 1) * 64);
        const float* xb = (const float*)(arena + buf * 8192);
        const _Float16* wb = (const _Float16*)(arena + 16384 + buf * 24576);
        half8 a[2];
        #pragma unroll
        for (int kc = 0; kc < 2; ++kc) {
            const int s0 = kc * 8 + quad * 2;
            f32x4 u0 = *(const f32x4*)(xb + xrow * 64 + ((s0    ) ^ (l15 & 15)) * 4);
            f32x4 u1 = *(const f32x4*)(xb + xrow * 64 + ((s0 + 1) ^ (l15 & 15)) * 4);
            a[kc][0] = (_Float16)u0[0]; a[kc][1] = (_Float16)u0[1];
            a[kc][2] = (_Float16)u0[2]; a[kc][3] = (_Float16)u0[3];
            a[kc][4] = (_Float16)u1[0]; a[kc][5] = (_Float16)u1[1];
            a[kc][6] = (_Float16)u1[2]; a[kc][7] = (_Float16)u1[3];
        }
        #pragma unroll
        for (int j = 0; j < 3; ++j) {
            const int dd = (grp * 3 + j) * 16 + l15;
            #pragma unroll
            for (int kc = 0; kc < 2; ++kc) {
                half8 bfr = *(const half8*)(wb + dd * 64
                              + (((kc * 4 + quad) ^ (l15 & 7)) * 8));
                acc[j] = __builtin_amdgcn_mfma_f32_16x16x32_f16(a[kc], bfr, acc[j], 0, 0, 0);
            }
        }
        __syncthreads();
    }

    #pragma unroll
    for (int j = 0; j < 3; ++j) {
        const int c = grp * 3 + j, m = c >> 2, n = c & 3;
        if (m < 2) {
            _Float16* __restrict__ dst = (m == 0) ? qh : kh;
            #pragma unroll
            for (int r = 0; r < 4; ++r)
                dst[(size_t)(row0 + strip * 16 + quad * 4 + r) * HD + n * 16 + l15] =
                    (_Float16)acc[j][r];
        } else {
            const int rg = row0 + strip * 16 + quad * 4;
            const int b = rg >> 11, s = rg & 2047;
            half4 h;
            h[0] = (_Float16)acc[j][0]; h[1] = (_Float16)acc[j][1];
            h[2] = (_Float16)acc[j][2]; h[3] = (_Float16)acc[j][3];
            *(half4*)(vpt + ((size_t)b * HD + n * 16 + l15) * SEQ + s) = h;
        }
    }
}

// ---------------- Column-softmax partial denominators (64-key blocks) ------
// grid (32,8,2) x 256 thr (4 waves). Block = 64 keys (ka[4][2] A-frags in
// regs); z = query-half: 16 DMA'd chunks of 64 queries, double-buffered,
// swizzled; wave w -> queries w*16 of each chunk. 8 MFMA per 2-DMA chunk
// per wave (2x the 32-key version). Writes RAW partial sums l_part[z][b][key].
__global__ __launch_bounds__(256) void stats_kernel(
    const _Float16* __restrict__ qh, const _Float16* __restrict__ kh,
    float* __restrict__ l_part)
{
    __shared__ __align__(16) char arena[16384];  // q: 2x8KB
    __shared__ float red[4][64];
    const int t = threadIdx.x, lane = t & 63, wave = t >> 6;
    const int l15 = lane & 15, quad = lane >> 4;
    const int b = blockIdx.y, c0 = blockIdx.x * 64, z = blockIdx.z;
    const int qbase = z * 1024;

    half8 ka[4][2];
    #pragma unroll
    for (int kt = 0; kt < 4; ++kt) {
        const _Float16* kp = kh + ((size_t)b * SEQ + c0 + kt * 16 + l15) * HD + quad * 8;
        ka[kt][0] = *(const half8*)(kp);
        ka[kt][1] = *(const half8*)(kp + 32);
    }

    auto issue = [&](int buf, int q0) {
        #pragma unroll
        for (int jj = 0; jj < 2; ++jj) {
            const int j = wave * 2 + jj;
            const int qq = j * 8 + (lane >> 3);
            const int logi = (lane & 7) ^ (qq & 7);
            dma16((_Float16*)(arena + buf * 8192) + j * 512,
                  qh + ((size_t)b * SEQ + q0 + qq) * HD + logi * 8);
        }
    };

    issue(0, qbase);
    __syncthreads();

    float csum[4][4] = {};
    const int qrow = wave * 16 + l15;
    for (int it = 0; it < 16; ++it) {
        const int buf = it & 1;
        if (it + 1 < 16) issue(buf ^ 1, qbase + (it + 1) * 64);
        const _Float16* qb = (const _Float16*)(arena + buf * 8192);
        half8 bq0 = *(const half8*)(qb + qrow * 64 + (((quad    ) ^ (l15 & 7)) * 8));
        half8 bq1 = *(const half8*)(qb + qrow * 64 + (((4 + quad) ^ (l15 & 7)) * 8));
        #pragma unroll
        for (int kt = 0; kt < 4; ++kt) {
            f32x4 s = {};
            s = __builtin_amdgcn_mfma_f32_16x16x32_f16(ka[kt][0], bq0, s, 0, 0, 0);
            s = __builtin_amdgcn_mfma_f32_16x16x32_f16(ka[kt][1], bq1, s, 0, 0, 0);
            #pragma unroll
            for (int r = 0; r < 4; ++r)
                csum[kt][r] += fexp2(s[r]);
        }
        __syncthreads();
    }
    #pragma unroll
    for (int kt = 0; kt < 4; ++kt)
        #pragma unroll
        for (int r = 0; r < 4; ++r) {
            csum[kt][r] += __shfl_xor(csum[kt][r], 1);
            csum[kt][r] += __shfl_xor(csum[kt][r], 2);
            csum[kt][r] += __shfl_xor(csum[kt][r], 4);
            csum[kt][r] += __shfl_xor(csum[kt][r], 8);
        }
    if (l15 == 0) {
        #pragma unroll
        for (int kt = 0; kt < 4; ++kt)
            #pragma unroll
            for (int r = 0; r < 4; ++r)
                red[wave][kt * 16 + quad * 4 + r] = csum[kt][r];
    }
    __syncthreads();
    if (t < 64)
        l_part[(size_t)z * BS + (size_t)b * SEQ + c0 + t] =
            red[0][t] + red[1][t] + red[2][t] + red[3][t];
}

// ---------------- opart[z] = P~ @ v over key-half z (64-row blocks) --------
// grid (32,8,2) x 256 thr (4 waves). Block = 64 q-rows; wave w owns rows
// w*16..+15 over ALL 64 staged keys per chunk -> 16 wave-MFMA per 16KB
// staged chunk (2x r1's ratio), NO cross-wave reduction. k/v DMA'd,
// double-buffered, swizzled (r1-proven patterns); l = 1/(l0+l1) in regs.
// Wave-private P LDS round trip (stride 76: conflict-free writes, 2-way
// reads). Compact f32 partial write; x16 broadcast is bcast_kernel.
__global__ __launch_bounds__(256) void out_kernel(
    const _Float16* __restrict__ qh, const _Float16* __restrict__ kh,
    const _Float16* __restrict__ vpt, const float* __restrict__ l_part,
    float* __restrict__ opart)
{
    __shared__ __align__(16) char arena[42496];
    // [0,16384)      kbuf [2][64][64] fp16
    // [16384,32768)  vbuf [2][64][64] fp16
    // [32768,42496)  ps   [4 waves][16][76] fp16
    const int t = threadIdx.x, lane = t & 63, wave = t >> 6;
    const int l15 = lane & 15, quad = lane >> 4;
    const int b = blockIdx.y, r0 = blockIdx.x * 64, z = blockIdx.z;
    const int kbase = z * 1024;

    half8 aq[2];
    {
        const _Float16* qp = qh + ((size_t)b * SEQ + r0 + wave * 16 + l15) * HD + quad * 8;
        aq[0] = *(const half8*)(qp);
        aq[1] = *(const half8*)(qp + 32);
    }

    auto issue = [&](int buf, int c0) {
        #pragma unroll
        for (int jj = 0; jj < 4; ++jj) {
            if (wave < 2) {        // k: 8 instrs, 64 key-rows x 64B
                const int j = wave * 4 + jj;
                const int key = j * 8 + (lane >> 3);
                const int logi = (lane & 7) ^ (key & 7);
                dma16((_Float16*)(arena + buf * 8192) + j * 512,
                      kh + ((size_t)b * SEQ + c0 + key) * HD + logi * 8);
            } else {               // v: 8 instrs (vpt is [b][d][s])
                const int j = (wave - 2) * 4 + jj;
                const int d = j * 8 + (lane >> 3);
                const int logi = (lane & 7) ^ (d & 7);
                dma16((_Float16*)(arena + 16384 + buf * 8192) + j * 512,
                      vpt + ((size_t)b * HD + d) * SEQ + c0 + logi * 8);
            }
        }
    };

    const float* lp = l_part + (size_t)b * SEQ;   // z'=0; z'=1 at +BS

    issue(0, kbase);
    __syncthreads();

    _Float16* psb = (_Float16*)(arena + 32768) + wave * 1216;  // [16][76]
    f32x4 oacc[4] = {};
    for (int it = 0; it < 16; ++it) {
        const int buf = it & 1;
        if (it + 1 < 16) issue(buf ^ 1, kbase + (it + 1) * 64);
        const _Float16* kb = (const _Float16*)(arena + buf * 8192);
        const _Float16* vb = (const _Float16*)(arena + 16384 + buf * 8192);

        #pragma unroll
        for (int ct = 0; ct < 4; ++ct) {
            const int key = ct * 16 + l15;
            f32x4 s = {};
            half8 kf0 = *(const half8*)(kb + key * 64 + (((quad    ) ^ (l15 & 7)) * 8));
            half8 kf1 = *(const half8*)(kb + key * 64 + (((4 + quad) ^ (l15 & 7)) * 8));
            s = __builtin_amdgcn_mfma_f32_16x16x32_f16(aq[0], kf0, s, 0, 0, 0);
            s = __builtin_amdgcn_mfma_f32_16x16x32_f16(aq[1], kf1, s, 0, 0, 0);
            const int kg = kbase + it * 64 + key;
            const float li = frcp(lp[kg] + lp[BS + kg]);
            #pragma unroll
            for (int r = 0; r < 4; ++r)
                psb[(quad * 4 + r) * 76 + ct * 16 + l15] =
                    (_Float16)(fexp2(s[r]) * li);
        }
        half8 paA = *(const half8*)(psb + l15 * 76 + quad * 8);        // keys 0..31
        half8 paB = *(const half8*)(psb + l15 * 76 + 32 + quad * 8);   // keys 32..63
        #pragma unroll
        for (int n = 0; n < 4; ++n) {
            const int d = n * 16 + l15;
            half8 vfA = *(const half8*)(vb + d * 64 + (((quad    ) ^ (l15 & 7)) * 8));
            half8 vfB = *(const half8*)(vb + d * 64 + (((4 + quad) ^ (l15 & 7)) * 8));
            oacc[n] = __builtin_amdgcn_mfma_f32_16x16x32_f16(paA, vfA, oacc[n], 0, 0, 0);
            oacc[n] = __builtin_amdgcn_mfma_f32_16x16x32_f16(paB, vfB, oacc[n], 0, 0, 0);
        }
        __syncthreads();
    }

    // compact write: wave-private 16x64 f32 tile -> opart[z]
    #pragma unroll
    for (int n = 0; n < 4; ++n)
        #pragma unroll
        for (int r = 0; r < 4; ++r) {
            const int row = r0 + wave * 16 + quad * 4 + r;
            opart[(size_t)z * ((size_t)BS * HD)
                  + ((size_t)b * SEQ + row) * HD + n * 16 + l15] = oacc[n][r];
        }
}

// ---------------- out[b,s,h*64+d] = opart[0][b,s,d] + opart[1][b,s,d] -----
// Pure-BW broadcast: one block per (b,s) row; 256 threads cover the 1024-f32
// output row with one float4 each. Reads 8 MiB, writes 64 MiB, coalesced.
__global__ __launch_bounds__(256) void bcast_kernel(
    const float* __restrict__ opart, float* __restrict__ out)
{
    const int row = blockIdx.x;          // [0, BS)
    const int t = threadIdx.x;
    const int d = (t * 4) & 63;          // source offset within the 64-f32 O row
    const float* o0 = opart + (size_t)row * HD + d;
    const float* o1 = o0 + (size_t)BS * HD;
    float4 a = *(const float4*)o0;
    float4 c = *(const float4*)o1;
    float4 s;
    s.x = a.x + c.x; s.y = a.y + c.y; s.z = a.z + c.z; s.w = a.w + c.w;
    *(float4*)(out + (size_t)row * (HD * HEADS) + t * 4) = s;
}

extern "C" void kernel_launch(void* const* d_in, const int* in_sizes, int n_in,
                              void* d_out, int out_size, void* d_ws, size_t ws_size,
                              hipStream_t stream)
{
    const float* x  = (const float*)d_in[0];
    const float* Wq = (const float*)d_in[1];
    const float* Wk = (const float*)d_in[2];
    const float* Wv = (const float*)d_in[3];
    float* out = (float*)d_out;

    const size_t N = (size_t)BATCH * SEQ * HD;   // 1,048,576
    _Float16* qh  = (_Float16*)d_ws;
    _Float16* kh  = qh + N;
    _Float16* vpt = kh + N;
    _Float16* Wh  = vpt + N;                     // 3*64*1024 halves
    float* l_part = (float*)(Wh + 196608);       // [2][B][S] f32 (128 KB)
    float* opart  = l_part + 2 * BS;             // [2][B][S][64] f32 (8 MiB)

    wcvt_kernel <<<dim3(32, 3),    256, 0, stream>>>(Wq, Wk, Wv, Wh);
    qkv_kernel  <<<dim3(512),      512, 0, stream>>>(x, Wh, qh, kh, vpt);
    stats_kernel<<<dim3(32, 8, 2), 256, 0, stream>>>(qh, kh, l_part);
    out_kernel  <<<dim3(32, 8, 2), 256, 0, stream>>>(qh, kh, vpt, l_part, opart);
    bcast_kernel<<<dim3(BS),       256, 0, stream>>>(opart, out);
}

// Round 8
// 174.778 us; speedup vs baseline: 1.3748x; 1.0001x over previous
//
#include <hip/hip_runtime.h>

#define BATCH 8
#define SEQ   2048
#define EMB   1024
#define HD    64
#define HEADS 16
#define BS    (BATCH * SEQ)
#define LOG2E 1.4426950408889634f

typedef _Float16 half8 __attribute__((ext_vector_type(8)));
typedef _Float16 half4 __attribute__((ext_vector_type(4)));
typedef float    f32x4 __attribute__((ext_vector_type(4)));

__device__ __forceinline__ float fexp2(float x) {
#if __has_builtin(__builtin_amdgcn_exp2f)
    return __builtin_amdgcn_exp2f(x);
#else
    return exp2f(x);
#endif
}

__device__ __forceinline__ float frcp(float x) {
#if __has_builtin(__builtin_amdgcn_rcpf)
    return __builtin_amdgcn_rcpf(x);
#else
    return 1.0f / x;
#endif
}

// async global->LDS DMA: lane i deposits its element at lds_base + i*size.
// lds_base must be wave-uniform; gsrc is per-lane.
__device__ __forceinline__ void dma16(void* lds_base, const void* gsrc) {
    __builtin_amdgcn_global_load_lds(
        (const __attribute__((address_space(1))) unsigned int*)gsrc,
        (__attribute__((address_space(3))) unsigned int*)lds_base, 16, 0, 0);
}

// counted waits (T4): never drain to 0 mid-loop; N = outstanding loads allowed
#define VMCNT(N) asm volatile("s_waitcnt vmcnt(" #N ")" ::: "memory")
#define LGKM0()  asm volatile("s_waitcnt lgkmcnt(0)" ::: "memory")
#define SBAR()   __builtin_amdgcn_s_barrier()

// ---------------- W -> fp16 (Wq pre-scaled by log2e: scores in log2 domain)
__global__ __launch_bounds__(256) void wcvt_kernel(
    const float* __restrict__ Wq, const float* __restrict__ Wk,
    const float* __restrict__ Wv, _Float16* __restrict__ Wh)
{
    const int m = blockIdx.y;
    const float* src = (m == 0) ? Wq : (m == 1) ? Wk : Wv;
    const float scale = (m == 0) ? LOG2E : 1.0f;
    const int idx = (blockIdx.x * 256 + threadIdx.x) * 8;
    float4 f0 = *(const float4*)(src + idx);
    float4 f1 = *(const float4*)(src + idx + 4);
    half8 h;
    h[0] = (_Float16)(f0.x * scale); h[1] = (_Float16)(f0.y * scale);
    h[2] = (_Float16)(f0.z * scale); h[3] = (_Float16)(f0.w * scale);
    h[4] = (_Float16)(f1.x * scale); h[5] = (_Float16)(f1.y * scale);
    h[6] = (_Float16)(f1.z * scale); h[7] = (_Float16)(f1.w * scale);
    *(half8*)(Wh + (size_t)m * 65536 + idx) = h;
}

// ---------------- QKV projection (r1 tile, counted-vmcnt skeleton) ----------
// 512 blocks x 512 thr (8 waves). Block = 32 rows, 12 ctiles; wave: strip=(w&1),
// grp=(w>>1) -> 3 ctiles. Per wave per chunk: 4 dma16. Skeleton:
// compute -> s_barrier -> issue(it+2) -> vmcnt(4) -> s_barrier (no full drain).
__global__ __launch_bounds__(512) void qkv_kernel(
    const float* __restrict__ x, const _Float16* __restrict__ Wh,
    _Float16* __restrict__ qh, _Float16* __restrict__ kh, _Float16* __restrict__ vpt)
{
    __shared__ __align__(16) char arena[65536];  // x: 2x8KB, W: 2x24KB
    const int t = threadIdx.x, lane = t & 63, wave = t >> 6;
    const int l15 = lane & 15, quad = lane >> 4;
    const int strip = wave & 1, grp = wave >> 1;
    const int row0 = blockIdx.x * 32;

    auto issue = [&](int buf, int k0) {
        #pragma unroll
        for (int jj = 0; jj < 4; ++jj) {
            const int j = wave * 4 + jj;
            if (j < 8) {           // x: 8 instrs, 4 rows x 16 f32-segs each
                const int row = j * 4 + (lane >> 4);
                const int logi = (lane & 15) ^ (row & 15);
                dma16((float*)(arena + buf * 8192) + j * 256,
                      x + (size_t)(row0 + row) * EMB + k0 + logi * 4);
            } else {               // W: 24 instrs, 8 dd-rows x 8 half-segs each
                const int jw = j - 8;
                const int dd = jw * 8 + (lane >> 3);
                const int logi = (lane & 7) ^ (dd & 7);
                dma16((_Float16*)(arena + 16384 + buf * 24576) + jw * 512,
                      Wh + (size_t)(dd >> 6) * 65536 + (size_t)(dd & 63) * EMB
                         + k0 + logi * 8);
            }
        }
    };

    issue(0, 0);
    issue(1, 64);
    VMCNT(4);            // stage0 complete; stage1 (4/wave) still in flight
    SBAR();

    f32x4 acc[3] = {};
    const int xrow = strip * 16 + l15;
    for (int it = 0; it < 16; ++it) {
        const int buf = it & 1;
        const float* xb = (const float*)(arena + buf * 8192);
        const _Float16* wb = (const _Float16*)(arena + 16384 + buf * 24576);
        half8 a[2];
        #pragma unroll
        for (int kc = 0; kc < 2; ++kc) {
            const int s0 = kc * 8 + quad * 2;
            f32x4 u0 = *(const f32x4*)(xb + xrow * 64 + ((s0    ) ^ (l15 & 15)) * 4);
            f32x4 u1 = *(const f32x4*)(xb + xrow * 64 + ((s0 + 1) ^ (l15 & 15)) * 4);
            a[kc][0] = (_Float16)u0[0]; a[kc][1] = (_Float16)u0[1];
            a[kc][2] = (_Float16)u0[2]; a[kc][3] = (_Float16)u0[3];
            a[kc][4] = (_Float16)u1[0]; a[kc][5] = (_Float16)u1[1];
            a[kc][6] = (_Float16)u1[2]; a[kc][7] = (_Float16)u1[3];
        }
        #pragma unroll
        for (int j = 0; j < 3; ++j) {
            const int dd = (grp * 3 + j) * 16 + l15;
            #pragma unroll
            for (int kc = 0; kc < 2; ++kc) {
                half8 bfr = *(const half8*)(wb + dd * 64
                              + (((kc * 4 + quad) ^ (l15 & 7)) * 8));
                acc[j] = __builtin_amdgcn_mfma_f32_16x16x32_f16(a[kc], bfr, acc[j], 0, 0, 0);
            }
        }
        SBAR();                         // all waves done reading buf
        if (it + 2 < 16) {
            issue(buf, (it + 2) * 64);  // refill just-freed buffer
            VMCNT(4);                   // stage(it+1) done; stage(it+2) in flight
        } else {
            VMCNT(0);                   // tail drain
        }
        SBAR();
    }

    #pragma unroll
    for (int j = 0; j < 3; ++j) {
        const int c = grp * 3 + j, m = c >> 2, n = c & 3;
        if (m < 2) {
            _Float16* __restrict__ dst = (m == 0) ? qh : kh;
            #pragma unroll
            for (int r = 0; r < 4; ++r)
                dst[(size_t)(row0 + strip * 16 + quad * 4 + r) * HD + n * 16 + l15] =
                    (_Float16)acc[j][r];
        } else {
            const int rg = row0 + strip * 16 + quad * 4;
            const int b = rg >> 11, s = rg & 2047;
            half4 h;
            h[0] = (_Float16)acc[j][0]; h[1] = (_Float16)acc[j][1];
            h[2] = (_Float16)acc[j][2]; h[3] = (_Float16)acc[j][3];
            *(half4*)(vpt + ((size_t)b * HD + n * 16 + l15) * SEQ + s) = h;
        }
    }
}

// ---------------- Column-softmax partials (64-key blocks, counted vmcnt) ----
// grid (32,8,2) x 256 thr (4 waves). Block = 64 keys (ka[4][2] in regs);
// z = query-half: 16 chunks of 64 queries. Per wave per chunk: 2 dma16.
// compute -> s_barrier -> issue(it+2) -> vmcnt(2) -> s_barrier.
__global__ __launch_bounds__(256) void stats_kernel(
    const _Float16* __restrict__ qh, const _Float16* __restrict__ kh,
    float* __restrict__ l_part)
{
    __shared__ __align__(16) char arena[16384];  // q: 2x8KB
    __shared__ float red[4][64];
    const int t = threadIdx.x, lane = t & 63, wave = t >> 6;
    const int l15 = lane & 15, quad = lane >> 4;
    const int b = blockIdx.y, c0 = blockIdx.x * 64, z = blockIdx.z;
    const int qbase = z * 1024;

    half8 ka[4][2];
    #pragma unroll
    for (int kt = 0; kt < 4; ++kt) {
        const _Float16* kp = kh + ((size_t)b * SEQ + c0 + kt * 16 + l15) * HD + quad * 8;
        ka[kt][0] = *(const half8*)(kp);
        ka[kt][1] = *(const half8*)(kp + 32);
    }

    auto issue = [&](int buf, int q0) {
        #pragma unroll
        for (int jj = 0; jj < 2; ++jj) {
            const int j = wave * 2 + jj;
            const int qq = j * 8 + (lane >> 3);
            const int logi = (lane & 7) ^ (qq & 7);
            dma16((_Float16*)(arena + buf * 8192) + j * 512,
                  qh + ((size_t)b * SEQ + q0 + qq) * HD + logi * 8);
        }
    };

    issue(0, qbase);
    issue(1, qbase + 64);
    VMCNT(2);            // ka + stage0 retired (older); stage1 in flight
    SBAR();

    float csum[4][4] = {};
    const int qrow = wave * 16 + l15;
    for (int it = 0; it < 16; ++it) {
        const int buf = it & 1;
        const _Float16* qb = (const _Float16*)(arena + buf * 8192);
        half8 bq0 = *(const half8*)(qb + qrow * 64 + (((quad    ) ^ (l15 & 7)) * 8));
        half8 bq1 = *(const half8*)(qb + qrow * 64 + (((4 + quad) ^ (l15 & 7)) * 8));
        #pragma unroll
        for (int kt = 0; kt < 4; ++kt) {
            f32x4 s = {};
            s = __builtin_amdgcn_mfma_f32_16x16x32_f16(ka[kt][0], bq0, s, 0, 0, 0);
            s = __builtin_amdgcn_mfma_f32_16x16x32_f16(ka[kt][1], bq1, s, 0, 0, 0);
            #pragma unroll
            for (int r = 0; r < 4; ++r)
                csum[kt][r] += fexp2(s[r]);
        }
        SBAR();
        if (it + 2 < 16) {
            issue(buf, qbase + (it + 2) * 64);
            VMCNT(2);
        } else {
            VMCNT(0);
        }
        SBAR();
    }
    #pragma unroll
    for (int kt = 0; kt < 4; ++kt)
        #pragma unroll
        for (int r = 0; r < 4; ++r) {
            csum[kt][r] += __shfl_xor(csum[kt][r], 1);
            csum[kt][r] += __shfl_xor(csum[kt][r], 2);
            csum[kt][r] += __shfl_xor(csum[kt][r], 4);
            csum[kt][r] += __shfl_xor(csum[kt][r], 8);
        }
    if (l15 == 0) {
        #pragma unroll
        for (int kt = 0; kt < 4; ++kt)
            #pragma unroll
            for (int r = 0; r < 4; ++r)
                red[wave][kt * 16 + quad * 4 + r] = csum[kt][r];
    }
    __syncthreads();
    if (t < 64)
        l_part[(size_t)z * BS + (size_t)b * SEQ + c0 + t] =
            red[0][t] + red[1][t] + red[2][t] + red[3][t];
}

// ---------------- opart[z] = P~ @ v (64-row blocks, counted vmcnt) ---------
// grid (32,8,2) x 256 thr (4 waves). Wave w owns rows w*16..+15 over all 64
// staged keys/chunk. Per wave per chunk: 4 dma16 (waves 0-1 k, 2-3 v).
// 1/l preloaded into LDS once (keeps vmcnt pure-DMA). Wave-private P LDS
// round trip (stride 76). compute -> s_barrier -> issue(it+2) -> vmcnt(4)
// -> s_barrier. Compact f32 partial write; x16 broadcast in bcast_kernel.
__global__ __launch_bounds__(256) void out_kernel(
    const _Float16* __restrict__ qh, const _Float16* __restrict__ kh,
    const _Float16* __restrict__ vpt, const float* __restrict__ l_part,
    float* __restrict__ opart)
{
    __shared__ __align__(16) char arena[46592];
    // [0,16384)      kbuf [2][64][64] fp16
    // [16384,32768)  vbuf [2][64][64] fp16
    // [32768,42496)  ps   [4 waves][16][76] fp16
    // [42496,46592)  ls   [1024] f32 (1/l for this z-half)
    const int t = threadIdx.x, lane = t & 63, wave = t >> 6;
    const int l15 = lane & 15, quad = lane >> 4;
    const int b = blockIdx.y, r0 = blockIdx.x * 64, z = blockIdx.z;
    const int kbase = z * 1024;

    half8 aq[2];
    {
        const _Float16* qp = qh + ((size_t)b * SEQ + r0 + wave * 16 + l15) * HD + quad * 8;
        aq[0] = *(const half8*)(qp);
        aq[1] = *(const half8*)(qp + 32);
    }

    // 1/l preload: loads are consumed by frcp before the DMA issues below,
    // so they retire first and the in-loop vmcnt counts pure DMA.
    const float* lp = l_part + (size_t)b * SEQ;   // z'=0; z'=1 at +BS
    float* ls = (float*)(arena + 42496);
    for (int i = t; i < 1024; i += 256)
        ls[i] = frcp(lp[kbase + i] + lp[BS + kbase + i]);

    auto issue = [&](int buf, int c0) {
        #pragma unroll
        for (int jj = 0; jj < 4; ++jj) {
            if (wave < 2) {        // k: 8 instrs, 64 key-rows x 64B
                const int j = wave * 4 + jj;
                const int key = j * 8 + (lane >> 3);
                const int logi = (lane & 7) ^ (key & 7);
                dma16((_Float16*)(arena + buf * 8192) + j * 512,
                      kh + ((size_t)b * SEQ + c0 + key) * HD + logi * 8);
            } else {               // v: 8 instrs (vpt is [b][d][s])
                const int j = (wave - 2) * 4 + jj;
                const int d = j * 8 + (lane >> 3);
                const int logi = (lane & 7) ^ (d & 7);
                dma16((_Float16*)(arena + 16384 + buf * 8192) + j * 512,
                      vpt + ((size_t)b * HD + d) * SEQ + c0 + logi * 8);
            }
        }
    };

    issue(0, kbase);
    issue(1, kbase + 64);
    LGKM0();             // ls ds_writes visible to all waves after barrier
    VMCNT(4);            // aq+ls retired (older); stage0 done; stage1 in flight
    SBAR();

    _Float16* psb = (_Float16*)(arena + 32768) + wave * 1216;  // [16][76]
    f32x4 oacc[4] = {};
    for (int it = 0; it < 16; ++it) {
        const int buf = it & 1;
        const _Float16* kb = (const _Float16*)(arena + buf * 8192);
        const _Float16* vb = (const _Float16*)(arena + 16384 + buf * 8192);

        #pragma unroll
        for (int ct = 0; ct < 4; ++ct) {
            const int key = ct * 16 + l15;
            f32x4 s = {};
            half8 kf0 = *(const half8*)(kb + key * 64 + (((quad    ) ^ (l15 & 7)) * 8));
            half8 kf1 = *(const half8*)(kb + key * 64 + (((4 + quad) ^ (l15 & 7)) * 8));
            s = __builtin_amdgcn_mfma_f32_16x16x32_f16(aq[0], kf0, s, 0, 0, 0);
            s = __builtin_amdgcn_mfma_f32_16x16x32_f16(aq[1], kf1, s, 0, 0, 0);
            const float li = ls[it * 64 + key];
            #pragma unroll
            for (int r = 0; r < 4; ++r)
                psb[(quad * 4 + r) * 76 + ct * 16 + l15] =
                    (_Float16)(fexp2(s[r]) * li);
        }
        half8 paA = *(const half8*)(psb + l15 * 76 + quad * 8);        // keys 0..31
        half8 paB = *(const half8*)(psb + l15 * 76 + 32 + quad * 8);   // keys 32..63
        #pragma unroll
        for (int n = 0; n < 4; ++n) {
            const int d = n * 16 + l15;
            half8 vfA = *(const half8*)(vb + d * 64 + (((quad    ) ^ (l15 & 7)) * 8));
            half8 vfB = *(const half8*)(vb + d * 64 + (((4 + quad) ^ (l15 & 7)) * 8));
            oacc[n] = __builtin_amdgcn_mfma_f32_16x16x32_f16(paA, vfA, oacc[n], 0, 0, 0);
            oacc[n] = __builtin_amdgcn_mfma_f32_16x16x32_f16(paB, vfB, oacc[n], 0, 0, 0);
        }
        SBAR();                         // all waves done reading buf
        if (it + 2 < 16) {
            issue(buf, kbase + (it + 2) * 64);
            VMCNT(4);                   // stage(it+1) done; stage(it+2) in flight
        } else {
            VMCNT(0);
        }
        SBAR();
    }

    // compact write: wave-private 16x64 f32 tile -> opart[z]
    #pragma unroll
    for (int n = 0; n < 4; ++n)
        #pragma unroll
        for (int r = 0; r < 4; ++r) {
            const int row = r0 + wave * 16 + quad * 4 + r;
            opart[(size_t)z * ((size_t)BS * HD)
                  + ((size_t)b * SEQ + row) * HD + n * 16 + l15] = oacc[n][r];
        }
}

// ---------------- out[b,s,h*64+d] = opart[0][b,s,d] + opart[1][b,s,d] -----
// Pure-BW broadcast: one block per (b,s) row; 256 threads cover the 1024-f32
// output row with one float4 each. Reads 8 MiB, writes 64 MiB, coalesced.
__global__ __launch_bounds__(256) void bcast_kernel(
    const float* __restrict__ opart, float* __restrict__ out)
{
    const int row = blockIdx.x;          // [0, BS)
    const int t = threadIdx.x;
    const int d = (t * 4) & 63;          // source offset within the 64-f32 O row
    const float* o0 = opart + (size_t)row * HD + d;
    const float* o1 = o0 + (size_t)BS * HD;
    float4 a = *(const float4*)o0;
    float4 c = *(const float4*)o1;
    float4 s;
    s.x = a.x + c.x; s.y = a.y + c.y; s.z = a.z + c.z; s.w = a.w + c.w;
    *(float4*)(out + (size_t)row * (HD * HEADS) + t * 4) = s;
}

extern "C" void kernel_launch(void* const* d_in, const int* in_sizes, int n_in,
                              void* d_out, int out_size, void* d_ws, size_t ws_size,
                              hipStream_t stream)
{
    const float* x  = (const float*)d_in[0];
    const float* Wq = (const float*)d_in[1];
    const float* Wk = (const float*)d_in[2];
    const float* Wv = (const float*)d_in[3];
    float* out = (float*)d_out;

    const size_t N = (size_t)BATCH * SEQ * HD;   // 1,048,576
    _Float16* qh  = (_Float16*)d_ws;
    _Float16* kh  = qh + N;
    _Float16* vpt = kh + N;
    _Float16* Wh  = vpt + N;                     // 3*64*1024 halves
    float* l_part = (float*)(Wh + 196608);       // [2][B][S] f32 (128 KB)
    float* opart  = l_part + 2 * BS;             // [2][B][S][64] f32 (8 MiB)

    wcvt_kernel <<<dim3(32, 3),    256, 0, stream>>>(Wq, Wk, Wv, Wh);
    qkv_kernel  <<<dim3(512),      512, 0, stream>>>(x, Wh, qh, kh, vpt);
    stats_kernel<<<dim3(32, 8, 2), 256, 0, stream>>>(qh, kh, l_part);
    out_kernel  <<<dim3(32, 8, 2), 256, 0, stream>>>(qh, kh, vpt, l_part, opart);
    bcast_kernel<<<dim3(BS),       256, 0, stream>>>(opart, out);
}